// Round 10
// baseline (163.627 us; speedup 1.0000x reference)
//
#include <hip/hip_runtime.h>
#include <stdint.h>

// Problem constants
#define B_   8
#define S_   2047
#define L_   2048      // S+1 (CLS prepended)
#define H_   256       // HIDDEN
#define NH_  8
#define HD_  32
#define V_   32001     // VOCAB+1
#define NCH_ 128       // t-chunks per b
#define TCH_ 16        // t per chunk (NCH_*TCH_ == L_)
#define GRID_ 1024     // 4 blocks/CU x 256 CU -> co-resident (proven r6/r8)
#define NREP_ 64       // replicas of broadcast data (qk, z)
#define BAR_STRIDE_ 2048   // u32 per flag region (8 KB)

// ---------------------------------------------------------------------------
// LLC-direct (coherent) access via relaxed agent-scope atomics (sc0 sc1 on
// gfx950 -> bypass L1/XCD-L2). Proven correct rounds 4-9.
// ---------------------------------------------------------------------------
__device__ __forceinline__ void ast(float* p, float v) {
    __hip_atomic_store((unsigned int*)p, __float_as_uint(v),
                       __ATOMIC_RELAXED, __HIP_MEMORY_SCOPE_AGENT);
}
__device__ __forceinline__ float ald(const float* p) {
    return __uint_as_float(__hip_atomic_load((const unsigned int*)p,
                           __ATOMIC_RELAXED, __HIP_MEMORY_SCOPE_AGENT));
}
__device__ __forceinline__ unsigned aadd(unsigned* p) {
    return __hip_atomic_fetch_add(p, 1u, __ATOMIC_RELAXED, __HIP_MEMORY_SCOPE_AGENT);
}
__device__ __forceinline__ unsigned aldu(const unsigned* p) {
    return __hip_atomic_load(p, __ATOMIC_RELAXED, __HIP_MEMORY_SCOPE_AGENT);
}
__device__ __forceinline__ void vdrain() {
    asm volatile("s_waitcnt vmcnt(0)" ::: "memory");
}
__device__ __forceinline__ float foldx(float a, int off) {
    return a + __shfl_xor(a, off, 64);
}
__device__ __forceinline__ float sel8(const float a[8], int j) {
    float v = a[0];
    v = (j == 1) ? a[1] : v;
    v = (j == 2) ? a[2] : v;
    v = (j == 3) ? a[3] : v;
    v = (j == 4) ? a[4] : v;
    v = (j == 5) ? a[5] : v;
    v = (j == 6) ? a[6] : v;
    v = (j == 7) ? a[7] : v;
    return v;
}

// ---------------------------------------------------------------------------
// Mega kernel, point-to-point flags; broadcast data 64x-replicated to kill
// LLC hot-line congestion (the shared ~70us floor of rounds 5/6/8):
//   P0 (blocks 0..7):  qk prep -> qk_rep[64 replicas] -> qflag
//   A  (all 1024):     prefetch toks/emb; poll qflag; stage qk from replica
//                      (bid&63); fused scores + cross-wave reduce ->
//                      streamed ast psum[bid][j] + padded ebar atomics -> acnt
//   R  (blocks 0..511): poll acnt==1024; parallel 128-chunk reduce of psum
//                      -> obar[b][j] -> rcnt
//   B  (blocks 0..7):  poll rcnt==512; normalize -> wv -> wo -> z ->
//                      z_rep[64 replicas] -> zflag
//   C  (all 1024, 32 rows): prefetch pass-0 wu (overlaps R/B); poll zflag;
//                      stage z from replica (bid&63); dot; out.
// LDS 33 KB, (256,4): VGPR<=128 (measured 56 in r8) -> 4 blocks/CU -> all
// 1024 co-resident -> flag protocol deadlock-free.
// ---------------------------------------------------------------------------
__global__ __launch_bounds__(256, 4) void mega(const int* __restrict__ x,
                                               const float* __restrict__ emb,
                                               const float* __restrict__ wq,
                                               const float* __restrict__ wk,
                                               const float* __restrict__ wv,
                                               const float* __restrict__ wo,
                                               const float* __restrict__ wu,
                                               float* __restrict__ out,
                                               float* __restrict__ qk_rep,
                                               float* __restrict__ z_rep,
                                               float* __restrict__ psum,
                                               float* __restrict__ obar,
                                               float* __restrict__ ebar_pad,
                                               unsigned int* __restrict__ bars) {
    int bid = blockIdx.x, tid = threadIdx.x;

    __shared__ float smem[4][2056];          // 32.9 KB, phase-aliased
    float* smf = &smem[0][0];

    unsigned* qbar = bars;                    // [0]=cnt, rel at [528+i*16] i<32
    unsigned* abar = bars + BAR_STRIDE_;      // same layout
    unsigned* rbar = bars + 2 * BAR_STRIDE_;  // [0]=cnt, rel at [528]
    unsigned* zbar = bars + 3 * BAR_STRIDE_;  // [0]=cnt, rel at [528+i*16]

    // ---- P0: qk prep (blocks 0..7) ----
    if (bid < NH_) {
        int n = bid;
        float* y0l = smem[0];
        float* q0p = smem[1];   // [k*8+p]
        float* q0l = smem[2];
        float v = emb[2 * H_ + tid] + ((tid & 1) ? 1.0f : 0.0f);  // pe[0]
        y0l[tid] = v;
        __syncthreads();
        {
            int k = tid >> 3, part = tid & 7;
            const float* w = wq + (n * HD_ + k) * H_ + part * 32;
            const float* yy = y0l + part * 32;
            float acc = 0.f;
#pragma unroll
            for (int j = 0; j < 32; ++j) acc += w[j] * yy[j];
            q0p[k * 8 + part] = acc;
        }
        __syncthreads();
        if (tid < HD_) {
            float s = 0.f;
#pragma unroll
            for (int j = 0; j < 8; ++j) s += q0p[tid * 8 + j];
            q0l[tid] = s;
        }
        __syncthreads();
        float acc = 0.f;
        for (int k = 0; k < HD_; ++k)
            acc += q0l[k] * wk[(n * HD_ + k) * H_ + tid];
        float qv = acc * 0.17677669529663687f;  // 1/sqrt(32)
        for (int r = 0; r < NREP_; ++r)
            ast(qk_rep + r * (NH_ * H_) + n * H_ + tid, qv);
        vdrain();
        __syncthreads();
        if (tid == 0) {
            if (aadd(qbar) == NH_ - 1) {
                for (int i = 0; i < 32; ++i)
                    __hip_atomic_store(qbar + 528 + i * 16, 1u,
                                       __ATOMIC_RELAXED, __HIP_MEMORY_SCOPE_AGENT);
            }
        }
        __syncthreads();
    }

    // ---- A: fused scores + chunk psum (all 1024 blocks) ----
    {
        int b = bid >> 7, c = bid & 127;
        int lane = tid & 63, w = tid >> 6;
        int h0 = lane * 4;
        int t0 = c * TCH_ + w * 4;

        // prefetch independent of qk
        int toks[4];
#pragma unroll
        for (int i = 0; i < 4; ++i) {
            int t = t0 + i;
            toks[i] = (t == 0) ? 2 : x[b * S_ + t - 1];
        }
        float4 evr[4];
#pragma unroll
        for (int i = 0; i < 4; ++i)
            evr[i] = *(const float4*)(emb + (size_t)toks[i] * H_ + h0);
        const float cdiv = 0.07195578414202881f;  // ln(10000)/128
        float div0 = __expf(-(float)(lane * 2) * cdiv);
        float div1 = __expf(-(float)(lane * 2 + 1) * cdiv);
        __builtin_amdgcn_sched_barrier(0);

        if (tid == 0) {
            while (aldu(qbar + 528 + (bid & 31) * 16) == 0u)
                __builtin_amdgcn_s_sleep(2);
        }
        __syncthreads();

        // stage qk from OWN replica (64x less per-line LLC traffic)
        const float* qsrc = qk_rep + (bid & (NREP_ - 1)) * (NH_ * H_);
        for (int i = tid; i < NH_ * H_; i += 256)
            smem[3][i] = ald(qsrc + i);
        __syncthreads();
        float4 qr[NH_];
#pragma unroll
        for (int n = 0; n < NH_; ++n)
            qr[n] = *(const float4*)&smem[3][n * H_ + h0];
        __syncthreads();   // smem[3] now dead -> red[3]

        float4 acc[NH_];
        float es[NH_];
#pragma unroll
        for (int n = 0; n < NH_; ++n) {
            acc[n] = make_float4(0.f, 0.f, 0.f, 0.f);
            es[n] = 0.f;
        }

#pragma unroll
        for (int i = 0; i < 4; ++i) {
            int t = t0 + i;
            float4 ev = evr[i];
            float a0 = (float)t * div0, a1 = (float)t * div1;
            float4 y4;
            y4.x = ev.x + __sinf(a0); y4.y = ev.y + __cosf(a0);
            y4.z = ev.z + __sinf(a1); y4.w = ev.w + __cosf(a1);

            float a[NH_];
#pragma unroll
            for (int n = 0; n < NH_; ++n)
                a[n] = qr[n].x * y4.x + qr[n].y * y4.y + qr[n].z * y4.z + qr[n].w * y4.w;

            float m4[4];
#pragma unroll
            for (int k = 0; k < 4; ++k) {
                float lo = foldx(a[k], 32), hi = foldx(a[k + 4], 32);
                m4[k] = (lane & 32) ? hi : lo;
            }
            float m2[2];
#pragma unroll
            for (int k = 0; k < 2; ++k) {
                float lo = foldx(m4[k], 16), hi = foldx(m4[k + 2], 16);
                m2[k] = (lane & 16) ? hi : lo;
            }
            float lo = foldx(m2[0], 8), hi = foldx(m2[1], 8);
            float m1 = (lane & 8) ? hi : lo;
            m1 = foldx(m1, 4); m1 = foldx(m1, 2); m1 = foldx(m1, 1);
            float e = __expf(m1);  // lane n*8 holds head n's score

#pragma unroll
            for (int n = 0; n < NH_; ++n) {
                float en = __shfl(e, n * 8, 64);
                acc[n].x += en * y4.x; acc[n].y += en * y4.y;
                acc[n].z += en * y4.z; acc[n].w += en * y4.w;
                es[n] += en;
            }
        }

#pragma unroll
        for (int n = 0; n < NH_; ++n)
            *(float4*)&smem[w][n * H_ + h0] = acc[n];
        if (lane < NH_) smem[w][2048 + lane] = sel8(es, lane);
        __syncthreads();

        // streamed psum (distributed addresses, no atomics)
#pragma unroll
        for (int jj = 0; jj < (NH_ * H_) / 256; ++jj) {
            int j = jj * 256 + tid;
            ast(psum + (size_t)bid * (NH_ * H_) + j,
                smem[0][j] + smem[1][j] + smem[2][j] + smem[3][j]);
        }
        if (tid < NH_)   // padded: one address per 64B line
            atomicAdd(ebar_pad + (b * NH_ + tid) * 16,
                      smem[0][2048 + tid] + smem[1][2048 + tid]
                    + smem[2][2048 + tid] + smem[3][2048 + tid]);
        vdrain();
        __syncthreads();
        if (tid == 0) {
            if (aadd(abar) == GRID_ - 1) {
                for (int i = 0; i < 32; ++i)
                    __hip_atomic_store(abar + 528 + i * 16, 1u,
                                       __ATOMIC_RELAXED, __HIP_MEMORY_SCOPE_AGENT);
            }
        }
        __syncthreads();
    }

    // ---- R: parallel psum reduce -> obar (blocks 0..511) ----
    if (bid < 512) {
        int b = bid >> 6;
        int j0 = (bid & 63) * 32;
        if (tid == 0) {
            while (aldu(abar + 528 + (bid & 31) * 16) == 0u)
                __builtin_amdgcn_s_sleep(2);
        }
        __syncthreads();
        int jl = tid & 31, cg = tid >> 5;        // 8 chunk-groups x 16 chunks
        float s = 0.f;
#pragma unroll 16
        for (int cc = cg * 16; cc < cg * 16 + 16; ++cc)
            s += ald(psum + (size_t)(b * NCH_ + cc) * (NH_ * H_) + j0 + jl);
        smf[jl * 8 + cg] = s;
        __syncthreads();
        if (tid < 32) {
            float t = 0.f;
#pragma unroll
            for (int g = 0; g < 8; ++g) t += smf[tid * 8 + g];
            ast(obar + b * (NH_ * H_) + j0 + tid, t);
        }
        vdrain();
        __syncthreads();
        if (tid == 0) {
            if (aadd(rbar) == 511u)
                __hip_atomic_store(rbar + 528, 1u,
                                   __ATOMIC_RELAXED, __HIP_MEMORY_SCOPE_AGENT);
        }
        __syncthreads();
    }

    // ---- B: normalize -> wv -> wo -> z -> z_rep (blocks 0..7) ----
    if (bid < B_) {
        int b = bid;
        if (tid == 0) {
            while (aldu(rbar + 528) == 0u) __builtin_amdgcn_s_sleep(2);
        }
        __syncthreads();
        float* ybar_l = smf;            // [2048]
        float* o_l    = smf + 2048;     // [256]
        float* sB     = smf + 2304;     // [8]
        if (tid < NH_) sB[tid] = 1.0f / ald(ebar_pad + (b * NH_ + tid) * 16);
        __syncthreads();
        for (int i = tid; i < NH_ * H_; i += 256)
            ybar_l[i] = ald(obar + b * (NH_ * H_) + i) * sB[i >> 8];
        __syncthreads();
        {   // wv: thread tid = n*32+k
            int n = tid >> 5;
            const float* wrow = wv + (size_t)tid * H_;
            const float* yy = ybar_l + n * H_;
            float s = 0.f;
#pragma unroll 16
            for (int j4 = 0; j4 < H_ / 4; ++j4) {
                float4 w4 = *(const float4*)(wrow + j4 * 4);
                s += w4.x * yy[j4 * 4] + w4.y * yy[j4 * 4 + 1]
                   + w4.z * yy[j4 * 4 + 2] + w4.w * yy[j4 * 4 + 3];
            }
            o_l[tid] = s;
        }
        __syncthreads();
        {   // wo + double residual; broadcast z to replicas
            float y0v = emb[2 * H_ + tid] + ((tid & 1) ? 1.0f : 0.0f);
            const float* wrow = wo + (size_t)tid * (NH_ * HD_);
            float s = 0.f;
#pragma unroll 16
            for (int j4 = 0; j4 < (NH_ * HD_) / 4; ++j4) {
                float4 w4 = *(const float4*)(wrow + j4 * 4);
                s += w4.x * o_l[j4 * 4] + w4.y * o_l[j4 * 4 + 1]
                   + w4.z * o_l[j4 * 4 + 2] + w4.w * o_l[j4 * 4 + 3];
            }
            float zv = s + 2.0f * y0v;
            for (int r = 0; r < NREP_; ++r)
                ast(z_rep + r * (B_ * H_) + b * H_ + tid, zv);
        }
        vdrain();
        __syncthreads();
        if (tid == 0) {
            if (aadd(zbar) == B_ - 1) {
                for (int i = 0; i < 32; ++i)
                    __hip_atomic_store(zbar + 528 + i * 16, 1u,
                                       __ATOMIC_RELAXED, __HIP_MEMORY_SCOPE_AGENT);
            }
        }
        __syncthreads();
    }

    // ---- C: out = z · wu^T (all blocks, 32 vocab rows each) ----
    {
        int lane = tid & 63, w = tid >> 6;
        int m = lane & 15, g = lane >> 4;
        int base = bid * 32;

        // pass-0 wu prefetch BEFORE the z poll (overlaps R/B)
        int rl0 = w * 4 + g;
        int v0 = base + rl0;
        int vc0 = (v0 < V_) ? v0 : (V_ - 1);
        const float* wr0 = wu + (size_t)vc0 * H_ + m * 16;
        float4 p00 = *(const float4*)(wr0);
        float4 p01 = *(const float4*)(wr0 + 4);
        float4 p02 = *(const float4*)(wr0 + 8);
        float4 p03 = *(const float4*)(wr0 + 12);
        __builtin_amdgcn_sched_barrier(0);

        if (tid == 0) {
            while (aldu(zbar + 528 + (bid & 31) * 16) == 0u)
                __builtin_amdgcn_s_sleep(2);
        }
        __syncthreads();

        // stage z from OWN replica, padded layout
        const float* zsrc = z_rep + (bid & (NREP_ - 1)) * (B_ * H_);
        float* zs = smf;                // [2560]
        float* sm_out = smf + 2560;     // [8*33]
        for (int i = tid; i < B_ * H_; i += 256) {
            int bb = i >> 8, h = i & 255;
            zs[bb * 320 + (h >> 4) * 20 + (h & 15)] = ald(zsrc + i);
        }
        __syncthreads();

#pragma unroll
        for (int pass = 0; pass < 2; ++pass) {
            int rl = pass * 16 + w * 4 + g;
            float4 w0, w1, w2, w3;
            if (pass == 0) { w0 = p00; w1 = p01; w2 = p02; w3 = p03; }
            else {
                int v = base + rl;
                int vc = (v < V_) ? v : (V_ - 1);
                const float* wr = wu + (size_t)vc * H_ + m * 16;
                w0 = *(const float4*)(wr);
                w1 = *(const float4*)(wr + 4);
                w2 = *(const float4*)(wr + 8);
                w3 = *(const float4*)(wr + 12);
            }
            float acc[B_];
#pragma unroll
            for (int bb = 0; bb < B_; ++bb) {
                const float* zb = zs + bb * 320 + m * 20;
                float4 z0 = *(const float4*)(zb);
                float4 z1 = *(const float4*)(zb + 4);
                float4 z2 = *(const float4*)(zb + 8);
                float4 z3 = *(const float4*)(zb + 12);
                acc[bb] = z0.x * w0.x + z0.y * w0.y + z0.z * w0.z + z0.w * w0.w
                        + z1.x * w1.x + z1.y * w1.y + z1.z * w1.z + z1.w * w1.w
                        + z2.x * w2.x + z2.y * w2.y + z2.z * w2.z + z2.w * w2.w
                        + z3.x * w3.x + z3.y * w3.y + z3.z * w3.z + z3.w * w3.w;
            }
#pragma unroll
            for (int off = 1; off <= 8; off <<= 1) {
#pragma unroll
                for (int bb = 0; bb < B_; ++bb) acc[bb] += __shfl_xor(acc[bb], off, 64);
            }
            if (m < B_) sm_out[m * 33 + rl] = sel8(acc, m);
        }
        __syncthreads();
        {
            int bb = tid >> 5, vl = tid & 31, vv = base + vl;
            if (vv < V_) out[bb * V_ + vv] = sm_out[bb * 33 + vl];
        }
    }
}

// ---------------------------------------------------------------------------
extern "C" void kernel_launch(void* const* d_in, const int* in_sizes, int n_in,
                              void* d_out, int out_size, void* d_ws, size_t ws_size,
                              hipStream_t stream) {
    const int*   x   = (const int*)d_in[0];
    const float* emb = (const float*)d_in[1];
    const float* wq  = (const float*)d_in[2];
    const float* wk  = (const float*)d_in[3];
    const float* wv  = (const float*)d_in[4];
    const float* wo  = (const float*)d_in[5];
    const float* wu  = (const float*)d_in[6];
    float*       out = (float*)d_out;

    // ws layout (floats unless noted), ~9.6 MiB:
    // qk_rep[64*2048] | z_rep[64*2048] | psum[1024*2048] | obar[8*2048]
    // | ebar_pad[64*16] | bars[4*2048 u32]
    float* qk_rep   = (float*)d_ws;
    float* z_rep    = qk_rep + (size_t)NREP_ * NH_ * H_;
    float* psum     = z_rep + (size_t)NREP_ * B_ * H_;
    float* obar     = psum + (size_t)GRID_ * NH_ * H_;
    float* ebar_pad = obar + B_ * NH_ * H_;
    unsigned int* bars = (unsigned int*)(ebar_pad + B_ * NH_ * 16);

    // Zero ebar + flags (contiguous; workspace is poisoned each iteration).
    hipMemsetAsync(ebar_pad, 0,
                   B_ * NH_ * 16 * sizeof(float)
                 + 4 * BAR_STRIDE_ * sizeof(unsigned int), stream);

    mega<<<GRID_, 256, 0, stream>>>(x, emb, wq, wk, wv, wo, wu, out,
                                    qk_rep, z_rep, psum, obar, ebar_pad, bars);
}